// Round 11
// baseline (124.944 us; speedup 1.0000x reference)
//
#include <hip/hip_runtime.h>
#include <math.h>

#define BATCH 8
#define CX 256
#define TC 512
#define CIN 768
#define HW_TOT 1024
#define NH 4
#define CHD 64

typedef __attribute__((ext_vector_type(8))) short short8;
typedef __attribute__((ext_vector_type(4))) short s4v;
typedef __attribute__((ext_vector_type(4))) float floatx4;
typedef __attribute__((ext_vector_type(4))) int int4v;

// softmax scale folded into Q: 0.125 * log2(e)
#define QSCALE 0.18033688f

// round-to-nearest-even f32 -> bf16
static __device__ __forceinline__ short f2bf(float f) {
    union { float f; unsigned u; } c; c.f = f;
    unsigned r = (c.u + 0x7fffu + ((c.u >> 16) & 1u)) >> 16;
    return (short)r;
}

// truncating pack of two f32 -> two bf16 in one int (lo in low half)
static __device__ __forceinline__ int pack_trunc(float lo, float hi) {
    union { float f; unsigned u; } L, H;
    L.f = lo; H.f = hi;
    return (int)((H.u & 0xffff0000u) | (L.u >> 16));
}

// ---------------------------------------------------------------------------
// Kernel 1: full GroupNorm -> per-(b,c) scale/shift; zeroes tc for prep's
// atomic text accumulation. Grid 256 x 256. (unchanged, proven)
// ---------------------------------------------------------------------------
__global__ __launch_bounds__(256)
void gn_kernel(const float* __restrict__ x, const float* __restrict__ tf,
               const float* __restrict__ gamma, const float* __restrict__ beta,
               float* __restrict__ scale, float* __restrict__ shift,
               float* __restrict__ tc) {
    const int b = blockIdx.x >> 5;
    const int g = blockIdx.x & 31;
    const int t = threadIdx.x;
    const int w = t >> 6, lane = t & 63;
    if (blockIdx.x < 24) tc[blockIdx.x * 256 + t] = 0.f;   // 6144 floats

    float s = 0.f, ss = 0.f;
    #pragma unroll
    for (int rr = 0; rr < 6; rr++) {
        const int row = w * 6 + rr;          // 0..23
        const int cg = g * 24 + row;
        if (cg < CX) {
            const float4* p = (const float4*)(x + ((size_t)b * CX + cg) * HW_TOT);
            #pragma unroll
            for (int i = 0; i < 4; i++) {
                float4 v = p[lane + 64 * i];
                s += v.x + v.y + v.z + v.w;
                ss += v.x * v.x + v.y * v.y + v.z * v.z + v.w * v.w;
            }
        } else {
            float v = tf[b * TC + cg - CX];
            s += 16.f * v;
            ss += 16.f * v * v;
        }
    }
    #pragma unroll
    for (int d = 1; d < 64; d <<= 1) {
        s += __shfl_xor(s, d);
        ss += __shfl_xor(ss, d);
    }
    __shared__ float rs_[4], rss_[4];
    if (lane == 0) { rs_[w] = s; rss_[w] = ss; }
    __syncthreads();
    const float S  = rs_[0] + rs_[1] + rs_[2] + rs_[3];
    const float SS = rss_[0] + rss_[1] + rss_[2] + rss_[3];
    const float inv_n = 1.f / (24 * 1024);
    const float mean = S * inv_n;
    const float var = SS * inv_n - mean * mean;
    const float r = rsqrtf(var + 1e-6f);
    if (t < 24) {
        int cg = g * 24 + t;
        float sc = gamma[cg] * r;
        scale[b * CIN + cg] = sc;
        shift[b * CIN + cg] = beta[cg] - mean * sc;
    }
}

// ---------------------------------------------------------------------------
// Kernel 2: merged prep: hnT transpose (blocks 0-255), W transpose (256-267),
// text contribution K-split x4 via atomicAdd (268-651). (unchanged, proven)
// ---------------------------------------------------------------------------
__global__ __launch_bounds__(256)
void prep_kernel(const float* __restrict__ x, const float* __restrict__ tf,
                 const float* __restrict__ scale, const float* __restrict__ shift,
                 const float* __restrict__ W0, const float* __restrict__ W1,
                 const float* __restrict__ W2,
                 short* __restrict__ hnT, short* __restrict__ Wt,
                 float* __restrict__ tc) {
    __shared__ float hs[128];
    __shared__ float red[4][64];
    const int bx = blockIdx.x;
    const int t = threadIdx.x;
    if (bx < 256) {
        int id = (bx & 31) * 256 + t;
        int b = id >> 10;
        const float* xb = x + (size_t)b * CX * HW_TOT + (id & 1023);
        const float* scb = scale + b * CIN;
        const float* shb = shift + b * CIN;
        short* outp = hnT + (size_t)id * CX;
        int c0base = (bx >> 5) * 32;
        for (int c0 = c0base; c0 < c0base + 32; c0 += 8) {
            short8 o;
            #pragma unroll
            for (int i = 0; i < 8; i++) {
                float v = xb[(size_t)(c0 + i) * HW_TOT];
                o[i] = f2bf(v * scb[c0 + i] + shb[c0 + i]);
            }
            *(short8*)(outp + c0) = o;
        }
    } else if (bx < 268) {
        int m = bx - 256;
        int dg = (m % 3) * 256 + t;
        int which = dg >> 8, d = dg & 255;
        const float* Wm = (which == 0) ? W0 : (which == 1) ? W1 : W2;
        int c0base = (m / 3) * 64;
        for (int c0 = c0base; c0 < c0base + 64; c0 += 8) {
            short8 o;
            #pragma unroll
            for (int i = 0; i < 8; i++) o[i] = f2bf(Wm[(size_t)(c0 + i) * CX + d]);
            *(short8*)(Wt + (size_t)dg * CX + c0) = o;
        }
    } else {
        // text contribution, K-split: block handles 128 of the 512 text rows
        int m = bx - 268;
        int ks = m & 3;
        int b = (m >> 2) & 7, dt = m >> 5;          // dt 0..11
        int which = dt >> 2, d0 = (dt & 3) * 64;
        const float* Wm = (which == 0) ? W0 : (which == 1) ? W1 : W2;
        if (t < 128) {
            int c = ks * 128 + t;
            hs[t] = tf[b * TC + c] * scale[b * CIN + CX + c] + shift[b * CIN + CX + c];
        }
        __syncthreads();
        int td = t & 63, tq = t >> 6;
        float acc = 0.f;
        const float* wp = Wm + (size_t)(CX + ks * 128 + tq * 32) * CX + d0 + td;
        #pragma unroll 8
        for (int c = 0; c < 32; c++)
            acc = fmaf(hs[tq * 32 + c], wp[(size_t)c * CX], acc);
        red[tq][td] = acc;
        __syncthreads();
        if (t < 64)
            atomicAdd(&tc[b * CIN + which * CX + d0 + t],
                      red[0][t] + red[1][t] + red[2][t] + red[3][t]);
    }
}

// ---------------------------------------------------------------------------
// Kernel 3: MFMA QKV GEMM, 64x64 tiles, BK=64. Q pre-scaled by QSCALE.
// q,k written [b][hw][256]; v written [b][256][1024]. (unchanged, proven)
// Grid (16 hw, 12 dt, 8 b) x 256.
// ---------------------------------------------------------------------------
__global__ __launch_bounds__(256)
void qkv_gemm(const short* __restrict__ hnT, const short* __restrict__ Wt,
              const float* __restrict__ tc,
              const float* __restrict__ b0, const float* __restrict__ b1,
              const float* __restrict__ b2,
              short* __restrict__ qb, short* __restrict__ kb, short* __restrict__ vb) {
    const int hw0 = blockIdx.x * 64, dt = blockIdx.y, b = blockIdx.z;
    const int which = dt >> 2;
    const int col0 = (dt & 3) * 64;
    const int dg0 = which * 256 + col0;
    const bool OV = (which == 2);

    __shared__ short At[64 * 72];
    __shared__ short Bt[64 * 72];

    const int t = threadIdx.x;
    const int w = t >> 6, l = t & 63;
    const int wm = w >> 1, wn = w & 1;
    const int l15 = l & 15, q = l >> 4;
    const int srow = t >> 2, sch = (t & 3) * 16;

    const short* gA = hnT + (size_t)(b * HW_TOT + hw0 + srow) * CX + sch;
    const short* gB = Wt + (size_t)(dg0 + srow) * CX + sch;

    floatx4 acc[2][2] = {};
    for (int k0 = 0; k0 < CX; k0 += 64) {
        __syncthreads();
        *(short8*)(At + srow * 72 + sch)     = *(const short8*)(gA + k0);
        *(short8*)(At + srow * 72 + sch + 8) = *(const short8*)(gA + k0 + 8);
        *(short8*)(Bt + srow * 72 + sch)     = *(const short8*)(gB + k0);
        *(short8*)(Bt + srow * 72 + sch + 8) = *(const short8*)(gB + k0 + 8);
        __syncthreads();
        const short* aB = OV ? Bt : At;
        const short* bB = OV ? At : Bt;
        #pragma unroll
        for (int kc = 0; kc < 2; kc++) {
            short8 af[2], bf2[2];
            #pragma unroll
            for (int mt = 0; mt < 2; mt++)
                af[mt] = *(const short8*)(aB + (wm * 32 + mt * 16 + l15) * 72 + kc * 32 + q * 8);
            #pragma unroll
            for (int nt = 0; nt < 2; nt++)
                bf2[nt] = *(const short8*)(bB + (wn * 32 + nt * 16 + l15) * 72 + kc * 32 + q * 8);
            #pragma unroll
            for (int mt = 0; mt < 2; mt++)
                #pragma unroll
                for (int nt = 0; nt < 2; nt++)
                    acc[mt][nt] = __builtin_amdgcn_mfma_f32_16x16x32_bf16(
                        af[mt], bf2[nt], acc[mt][nt], 0, 0, 0);
        }
    }

    __syncthreads();
    const float* bias = (which == 0) ? b0 : (which == 1) ? b1 : b2;
    if (!OV) {
        const float qs = (which == 0) ? QSCALE : 1.0f;
        float cadd[2];
        #pragma unroll
        for (int nt = 0; nt < 2; nt++) {
            int d = col0 + wn * 32 + nt * 16 + l15;
            cadd[nt] = bias[d] + tc[b * CIN + which * CX + d];
        }
        #pragma unroll
        for (int mt = 0; mt < 2; mt++)
            #pragma unroll
            for (int rr = 0; rr < 4; rr++)
                #pragma unroll
                for (int nt = 0; nt < 2; nt++)
                    At[(wm * 32 + mt * 16 + q * 4 + rr) * 72 + wn * 32 + nt * 16 + l15]
                        = f2bf((acc[mt][nt][rr] + cadd[nt]) * qs);
    } else {
        #pragma unroll
        for (int mt = 0; mt < 2; mt++)
            #pragma unroll
            for (int rr = 0; rr < 4; rr++) {
                int d = col0 + wm * 32 + mt * 16 + q * 4 + rr;
                float radd = bias[d] + tc[b * CIN + 2 * CX + d];
                #pragma unroll
                for (int nt = 0; nt < 2; nt++)
                    At[(wm * 32 + mt * 16 + q * 4 + rr) * 72 + wn * 32 + nt * 16 + l15]
                        = f2bf(acc[mt][nt][rr] + radd);
            }
    }
    __syncthreads();
    short8 v0 = *(const short8*)(At + srow * 72 + sch);
    short8 v1 = *(const short8*)(At + srow * 72 + sch + 8);
    if (!OV) {
        short* outp = (which == 0) ? qb : kb;
        size_t off = (size_t)(b * HW_TOT + hw0 + srow) * CX + col0 + sch;
        *(short8*)(outp + off) = v0;
        *(short8*)(outp + off + 8) = v1;
    } else {
        size_t off = (size_t)(b * CX + col0 + srow) * HW_TOT + hw0 + sch;
        *(short8*)(vb + off) = v0;
        *(short8*)(vb + off + 8) = v1;
    }
}

// ---------------------------------------------------------------------------
// Kernel 4: flash attention, 128-qi blocks: each wave owns 32 qi (2 groups),
// so the 16 ds_read_b128 of K/V per iter serve 2x the rows -> LDS and global
// K/V traffic halve vs the 64-qi version. Split-1, K/V double-buffered,
// Q pre-scaled (p = exp2f(s)), ones-MFMA l-sum, V swizzled for b128 A-frags,
// fused residual. Grid (8 qt, 32 bh) x 256.
// ---------------------------------------------------------------------------
__global__ __launch_bounds__(256)
void attn_kernel(const short* __restrict__ qb, const short* __restrict__ kb,
                 const short* __restrict__ vb, const float* __restrict__ x,
                 float* __restrict__ out) {
    const int qt = blockIdx.x, bh = blockIdx.y;
    const int b = bh >> 2, h = bh & 3;
    const int hw0 = qt * 128;

    __shared__ short Qs[128 * 72];
    __shared__ short Ks[2][64 * 72];
    __shared__ short Vs[2][64 * 72];

    const int t = threadIdx.x;
    const int w = t >> 6, l = t & 63;
    const int l15 = l & 15, q = l >> 4;
    const int srow = t >> 2, sch = (t & 3) * 16;
    const int vpos0 = ((sch >> 5) << 5) + ((sch >> 4) & 1) * 4;   // kcc*32+sub*4

    {   // stage Q tile [qi][c], 128 rows in 2 passes
        #pragma unroll
        for (int rr = 0; rr < 2; rr++) {
            const short* gq = qb + (size_t)(b * HW_TOT + hw0 + rr * 64 + srow) * CX
                            + h * CHD + sch;
            *(short8*)(Qs + (rr * 64 + srow) * 72 + sch)     = *(const short8*)gq;
            *(short8*)(Qs + (rr * 64 + srow) * 72 + sch + 8) = *(const short8*)(gq + 8);
        }
    }

    // prefetch tile 0 -> regs -> buf0 (V swizzled)
    short8 pk0, pk1, pv0, pv1;
    {
        const short* gk = kb + (size_t)(b * HW_TOT + 0 + srow) * CX + h * CHD + sch;
        pk0 = *(const short8*)gk;
        pk1 = *(const short8*)(gk + 8);
        const short* gv = vb + (size_t)(b * CX + h * CHD + srow) * HW_TOT + 0 + sch;
        pv0 = *(const short8*)gv;
        pv1 = *(const short8*)(gv + 8);
        *(short8*)(Ks[0] + srow * 72 + sch)     = pk0;
        *(short8*)(Ks[0] + srow * 72 + sch + 8) = pk1;
        short* vrow = Vs[0] + srow * 72 + vpos0;
        *(s4v*)(vrow)      = __builtin_shufflevector(pv0, pv0, 0, 1, 2, 3);
        *(s4v*)(vrow + 8)  = __builtin_shufflevector(pv0, pv0, 4, 5, 6, 7);
        *(s4v*)(vrow + 16) = __builtin_shufflevector(pv1, pv1, 0, 1, 2, 3);
        *(s4v*)(vrow + 24) = __builtin_shufflevector(pv1, pv1, 4, 5, 6, 7);
    }
    __syncthreads();

    // Q fragments for this wave's 2 qi-groups (qi = w*32 + g*16 + l15)
    short8 aq[2][2];
    #pragma unroll
    for (int g = 0; g < 2; g++) {
        aq[g][0] = *(const short8*)(Qs + (w * 32 + g * 16 + l15) * 72 + q * 8);
        aq[g][1] = *(const short8*)(Qs + (w * 32 + g * 16 + l15) * 72 + 32 + q * 8);
    }

    // all-ones bf16 A-fragment for the l-sum MFMA
    union { int4v i; short8 s; } ones;
    ones.i[0] = 0x3f803f80; ones.i[1] = 0x3f803f80;
    ones.i[2] = 0x3f803f80; ones.i[3] = 0x3f803f80;

    floatx4 oacc[2][4] = {};
    floatx4 lacc[2] = {};

    for (int jj = 0; jj < 16; jj++) {
        const int cur = jj & 1;
        if (jj < 15) {   // issue next tile's global loads early
            const int j0 = (jj + 1) * 64;
            const short* gk = kb + (size_t)(b * HW_TOT + j0 + srow) * CX + h * CHD + sch;
            pk0 = *(const short8*)gk;
            pk1 = *(const short8*)(gk + 8);
            const short* gv = vb + (size_t)(b * CX + h * CHD + srow) * HW_TOT + j0 + sch;
            pv0 = *(const short8*)gv;
            pv1 = *(const short8*)(gv + 8);
        }

        // S^T = K . Q'^T : C[m=kj][n=qi]; K frags shared across both groups
        const short* Kc = Ks[cur];
        floatx4 sacc[2][4] = {};
        #pragma unroll
        for (int nt = 0; nt < 4; nt++) {
            short8 kf0 = *(const short8*)(Kc + (nt * 16 + l15) * 72 + q * 8);
            short8 kf1 = *(const short8*)(Kc + (nt * 16 + l15) * 72 + 32 + q * 8);
            #pragma unroll
            for (int g = 0; g < 2; g++) {
                sacc[g][nt] = __builtin_amdgcn_mfma_f32_16x16x32_bf16(kf0, aq[g][0], sacc[g][nt], 0, 0, 0);
                sacc[g][nt] = __builtin_amdgcn_mfma_f32_16x16x32_bf16(kf1, aq[g][1], sacc[g][nt], 0, 0, 0);
            }
        }

        // p = exp2(s'); truncating pack into B-operand registers (per group)
        union { int4v i; short8 s; } u[2][2];
        #pragma unroll
        for (int g = 0; g < 2; g++)
            #pragma unroll
            for (int nt = 0; nt < 4; nt++) {
                float e0 = exp2f(sacc[g][nt][0]);
                float e1 = exp2f(sacc[g][nt][1]);
                float e2 = exp2f(sacc[g][nt][2]);
                float e3 = exp2f(sacc[g][nt][3]);
                u[g][nt >> 1].i[(nt & 1) * 2]     = pack_trunc(e0, e1);
                u[g][nt >> 1].i[(nt & 1) * 2 + 1] = pack_trunc(e2, e3);
            }

        // l += 1^T . P
        #pragma unroll
        for (int g = 0; g < 2; g++) {
            lacc[g] = __builtin_amdgcn_mfma_f32_16x16x32_bf16(ones.s, u[g][0].s, lacc[g], 0, 0, 0);
            lacc[g] = __builtin_amdgcn_mfma_f32_16x16x32_bf16(ones.s, u[g][1].s, lacc[g], 0, 0, 0);
        }

        // O^T += V^T . P : V frags (single b128, swizzled) shared across groups
        const short* Vc = Vs[cur];
        #pragma unroll
        for (int ct = 0; ct < 4; ct++) {
            const short* vr = Vc + (ct * 16 + l15) * 72;
            #pragma unroll
            for (int kcc = 0; kcc < 2; kcc++) {
                short8 vf = *(const short8*)(vr + kcc * 32 + q * 8);
                #pragma unroll
                for (int g = 0; g < 2; g++)
                    oacc[g][ct] = __builtin_amdgcn_mfma_f32_16x16x32_bf16(
                        vf, u[g][kcc].s, oacc[g][ct], 0, 0, 0);
            }
        }

        if (jj < 15) {   // store next tile into the other buffer; 1 barrier/iter
            __syncthreads();   // all reads of buf done before overwrite? (dbuf: writes go to OTHER buf)
            *(short8*)(Ks[1 - cur] + srow * 72 + sch)     = pk0;
            *(short8*)(Ks[1 - cur] + srow * 72 + sch + 8) = pk1;
            short* vrow = Vs[1 - cur] + srow * 72 + vpos0;
            *(s4v*)(vrow)      = __builtin_shufflevector(pv0, pv0, 0, 1, 2, 3);
            *(s4v*)(vrow + 8)  = __builtin_shufflevector(pv0, pv0, 4, 5, 6, 7);
            *(s4v*)(vrow + 16) = __builtin_shufflevector(pv1, pv1, 0, 1, 2, 3);
            *(s4v*)(vrow + 24) = __builtin_shufflevector(pv1, pv1, 4, 5, 6, 7);
            __syncthreads();
        }
    }

    // epilogue: normalize, residual, write out (per group)
    #pragma unroll
    for (int g = 0; g < 2; g++) {
        const float rinv = 1.f / lacc[g][0];
        #pragma unroll
        for (int ct = 0; ct < 4; ct++)
            #pragma unroll
            for (int r = 0; r < 4; r++) {
                int c = h * CHD + ct * 16 + q * 4 + r;
                size_t idx = (size_t)(b * CX + c) * HW_TOT + hw0 + w * 32 + g * 16 + l15;
                out[idx] = x[idx] + oacc[g][ct][r] * rinv;
            }
    }
}

// ---------------------------------------------------------------------------
extern "C" void kernel_launch(void* const* d_in, const int* in_sizes, int n_in,
                              void* d_out, int out_size, void* d_ws, size_t ws_size,
                              hipStream_t stream) {
    (void)in_sizes; (void)n_in; (void)out_size; (void)ws_size;
    const float* x     = (const float*)d_in[0];
    const float* tf    = (const float*)d_in[1];
    const float* gamma = (const float*)d_in[2];
    const float* beta  = (const float*)d_in[3];
    const float* W0 = (const float*)d_in[4];
    const float* b0 = (const float*)d_in[5];
    const float* W1 = (const float*)d_in[6];
    const float* b1 = (const float*)d_in[7];
    const float* W2 = (const float*)d_in[8];
    const float* b2 = (const float*)d_in[9];

    char* ws = (char*)d_ws;
    float* scale  = (float*)(ws);                 // 24576 B
    float* shift  = (float*)(ws + 24576);         // 24576 B
    float* tcb    = (float*)(ws + 49152);         // 24576 B
    short* Wt     = (short*)(ws + 73728);         // 393216 B
    short* hnT    = (short*)(ws + 466944);        // 4 MiB
    short* qb     = (short*)(ws + 4661248);       // 4 MiB
    short* kb     = (short*)(ws + 8855552);       // 4 MiB
    short* vb     = (short*)(ws + 13049856);      // 4 MiB

    hipLaunchKernelGGL(gn_kernel, dim3(256), dim3(256), 0, stream,
                       x, tf, gamma, beta, scale, shift, tcb);
    hipLaunchKernelGGL(prep_kernel, dim3(652), dim3(256), 0, stream,
                       x, tf, scale, shift, W0, W1, W2, hnT, Wt, tcb);
    hipLaunchKernelGGL(qkv_gemm, dim3(16, 12, BATCH), dim3(256), 0, stream,
                       hnT, Wt, tcb, b0, b1, b2, qb, kb, vb);
    hipLaunchKernelGGL(attn_kernel, dim3(8, 32), dim3(256), 0, stream,
                       qb, kb, vb, x, (float*)d_out);
}

// Round 12
// 118.626 us; speedup vs baseline: 1.0533x; 1.0533x over previous
//
#include <hip/hip_runtime.h>
#include <math.h>

#define BATCH 8
#define CX 256
#define TC 512
#define CIN 768
#define HW_TOT 1024
#define NH 4
#define CHD 64

typedef __attribute__((ext_vector_type(8))) short short8;
typedef __attribute__((ext_vector_type(4))) short s4v;
typedef __attribute__((ext_vector_type(4))) float floatx4;
typedef __attribute__((ext_vector_type(4))) int int4v;

// softmax scale folded into Q: 0.125 * log2(e)
#define QSCALE 0.18033688f

// round-to-nearest-even f32 -> bf16
static __device__ __forceinline__ short f2bf(float f) {
    union { float f; unsigned u; } c; c.f = f;
    unsigned r = (c.u + 0x7fffu + ((c.u >> 16) & 1u)) >> 16;
    return (short)r;
}

// truncating pack of two f32 -> two bf16 in one int (lo in low half)
static __device__ __forceinline__ int pack_trunc(float lo, float hi) {
    union { float f; unsigned u; } L, H;
    L.f = lo; H.f = hi;
    return (int)((H.u & 0xffff0000u) | (L.u >> 16));
}

// ---------------------------------------------------------------------------
// Kernel 1: full GroupNorm -> per-(b,c) scale/shift; zeroes tc for prep's
// atomic text accumulation. Grid 256 x 256. (unchanged, proven)
// ---------------------------------------------------------------------------
__global__ __launch_bounds__(256)
void gn_kernel(const float* __restrict__ x, const float* __restrict__ tf,
               const float* __restrict__ gamma, const float* __restrict__ beta,
               float* __restrict__ scale, float* __restrict__ shift,
               float* __restrict__ tc) {
    const int b = blockIdx.x >> 5;
    const int g = blockIdx.x & 31;
    const int t = threadIdx.x;
    const int w = t >> 6, lane = t & 63;
    if (blockIdx.x < 24) tc[blockIdx.x * 256 + t] = 0.f;   // 6144 floats

    float s = 0.f, ss = 0.f;
    #pragma unroll
    for (int rr = 0; rr < 6; rr++) {
        const int row = w * 6 + rr;          // 0..23
        const int cg = g * 24 + row;
        if (cg < CX) {
            const float4* p = (const float4*)(x + ((size_t)b * CX + cg) * HW_TOT);
            #pragma unroll
            for (int i = 0; i < 4; i++) {
                float4 v = p[lane + 64 * i];
                s += v.x + v.y + v.z + v.w;
                ss += v.x * v.x + v.y * v.y + v.z * v.z + v.w * v.w;
            }
        } else {
            float v = tf[b * TC + cg - CX];
            s += 16.f * v;
            ss += 16.f * v * v;
        }
    }
    #pragma unroll
    for (int d = 1; d < 64; d <<= 1) {
        s += __shfl_xor(s, d);
        ss += __shfl_xor(ss, d);
    }
    __shared__ float rs_[4], rss_[4];
    if (lane == 0) { rs_[w] = s; rss_[w] = ss; }
    __syncthreads();
    const float S  = rs_[0] + rs_[1] + rs_[2] + rs_[3];
    const float SS = rss_[0] + rss_[1] + rss_[2] + rss_[3];
    const float inv_n = 1.f / (24 * 1024);
    const float mean = S * inv_n;
    const float var = SS * inv_n - mean * mean;
    const float r = rsqrtf(var + 1e-6f);
    if (t < 24) {
        int cg = g * 24 + t;
        float sc = gamma[cg] * r;
        scale[b * CIN + cg] = sc;
        shift[b * CIN + cg] = beta[cg] - mean * sc;
    }
}

// ---------------------------------------------------------------------------
// Kernel 2: merged prep: hnT transpose (blocks 0-255), W transpose (256-267),
// text contribution K-split x4 via atomicAdd (268-651). (unchanged, proven)
// ---------------------------------------------------------------------------
__global__ __launch_bounds__(256)
void prep_kernel(const float* __restrict__ x, const float* __restrict__ tf,
                 const float* __restrict__ scale, const float* __restrict__ shift,
                 const float* __restrict__ W0, const float* __restrict__ W1,
                 const float* __restrict__ W2,
                 short* __restrict__ hnT, short* __restrict__ Wt,
                 float* __restrict__ tc) {
    __shared__ float hs[128];
    __shared__ float red[4][64];
    const int bx = blockIdx.x;
    const int t = threadIdx.x;
    if (bx < 256) {
        int id = (bx & 31) * 256 + t;
        int b = id >> 10;
        const float* xb = x + (size_t)b * CX * HW_TOT + (id & 1023);
        const float* scb = scale + b * CIN;
        const float* shb = shift + b * CIN;
        short* outp = hnT + (size_t)id * CX;
        int c0base = (bx >> 5) * 32;
        for (int c0 = c0base; c0 < c0base + 32; c0 += 8) {
            short8 o;
            #pragma unroll
            for (int i = 0; i < 8; i++) {
                float v = xb[(size_t)(c0 + i) * HW_TOT];
                o[i] = f2bf(v * scb[c0 + i] + shb[c0 + i]);
            }
            *(short8*)(outp + c0) = o;
        }
    } else if (bx < 268) {
        int m = bx - 256;
        int dg = (m % 3) * 256 + t;
        int which = dg >> 8, d = dg & 255;
        const float* Wm = (which == 0) ? W0 : (which == 1) ? W1 : W2;
        int c0base = (m / 3) * 64;
        for (int c0 = c0base; c0 < c0base + 64; c0 += 8) {
            short8 o;
            #pragma unroll
            for (int i = 0; i < 8; i++) o[i] = f2bf(Wm[(size_t)(c0 + i) * CX + d]);
            *(short8*)(Wt + (size_t)dg * CX + c0) = o;
        }
    } else {
        // text contribution, K-split: block handles 128 of the 512 text rows
        int m = bx - 268;
        int ks = m & 3;
        int b = (m >> 2) & 7, dt = m >> 5;          // dt 0..11
        int which = dt >> 2, d0 = (dt & 3) * 64;
        const float* Wm = (which == 0) ? W0 : (which == 1) ? W1 : W2;
        if (t < 128) {
            int c = ks * 128 + t;
            hs[t] = tf[b * TC + c] * scale[b * CIN + CX + c] + shift[b * CIN + CX + c];
        }
        __syncthreads();
        int td = t & 63, tq = t >> 6;
        float acc = 0.f;
        const float* wp = Wm + (size_t)(CX + ks * 128 + tq * 32) * CX + d0 + td;
        #pragma unroll 8
        for (int c = 0; c < 32; c++)
            acc = fmaf(hs[tq * 32 + c], wp[(size_t)c * CX], acc);
        red[tq][td] = acc;
        __syncthreads();
        if (t < 64)
            atomicAdd(&tc[b * CIN + which * CX + d0 + t],
                      red[0][t] + red[1][t] + red[2][t] + red[3][t]);
    }
}

// ---------------------------------------------------------------------------
// Kernel 3: MFMA QKV GEMM, 64x64 tiles, BK=64. Q pre-scaled by QSCALE.
// q,k written [b][hw][256]; v written [b][256][1024]. (unchanged, proven)
// Grid (16 hw, 12 dt, 8 b) x 256.
// ---------------------------------------------------------------------------
__global__ __launch_bounds__(256)
void qkv_gemm(const short* __restrict__ hnT, const short* __restrict__ Wt,
              const float* __restrict__ tc,
              const float* __restrict__ b0, const float* __restrict__ b1,
              const float* __restrict__ b2,
              short* __restrict__ qb, short* __restrict__ kb, short* __restrict__ vb) {
    const int hw0 = blockIdx.x * 64, dt = blockIdx.y, b = blockIdx.z;
    const int which = dt >> 2;
    const int col0 = (dt & 3) * 64;
    const int dg0 = which * 256 + col0;
    const bool OV = (which == 2);

    __shared__ short At[64 * 72];
    __shared__ short Bt[64 * 72];

    const int t = threadIdx.x;
    const int w = t >> 6, l = t & 63;
    const int wm = w >> 1, wn = w & 1;
    const int l15 = l & 15, q = l >> 4;
    const int srow = t >> 2, sch = (t & 3) * 16;

    const short* gA = hnT + (size_t)(b * HW_TOT + hw0 + srow) * CX + sch;
    const short* gB = Wt + (size_t)(dg0 + srow) * CX + sch;

    floatx4 acc[2][2] = {};
    for (int k0 = 0; k0 < CX; k0 += 64) {
        __syncthreads();
        *(short8*)(At + srow * 72 + sch)     = *(const short8*)(gA + k0);
        *(short8*)(At + srow * 72 + sch + 8) = *(const short8*)(gA + k0 + 8);
        *(short8*)(Bt + srow * 72 + sch)     = *(const short8*)(gB + k0);
        *(short8*)(Bt + srow * 72 + sch + 8) = *(const short8*)(gB + k0 + 8);
        __syncthreads();
        const short* aB = OV ? Bt : At;
        const short* bB = OV ? At : Bt;
        #pragma unroll
        for (int kc = 0; kc < 2; kc++) {
            short8 af[2], bf2[2];
            #pragma unroll
            for (int mt = 0; mt < 2; mt++)
                af[mt] = *(const short8*)(aB + (wm * 32 + mt * 16 + l15) * 72 + kc * 32 + q * 8);
            #pragma unroll
            for (int nt = 0; nt < 2; nt++)
                bf2[nt] = *(const short8*)(bB + (wn * 32 + nt * 16 + l15) * 72 + kc * 32 + q * 8);
            #pragma unroll
            for (int mt = 0; mt < 2; mt++)
                #pragma unroll
                for (int nt = 0; nt < 2; nt++)
                    acc[mt][nt] = __builtin_amdgcn_mfma_f32_16x16x32_bf16(
                        af[mt], bf2[nt], acc[mt][nt], 0, 0, 0);
        }
    }

    __syncthreads();
    const float* bias = (which == 0) ? b0 : (which == 1) ? b1 : b2;
    if (!OV) {
        const float qs = (which == 0) ? QSCALE : 1.0f;
        float cadd[2];
        #pragma unroll
        for (int nt = 0; nt < 2; nt++) {
            int d = col0 + wn * 32 + nt * 16 + l15;
            cadd[nt] = bias[d] + tc[b * CIN + which * CX + d];
        }
        #pragma unroll
        for (int mt = 0; mt < 2; mt++)
            #pragma unroll
            for (int rr = 0; rr < 4; rr++)
                #pragma unroll
                for (int nt = 0; nt < 2; nt++)
                    At[(wm * 32 + mt * 16 + q * 4 + rr) * 72 + wn * 32 + nt * 16 + l15]
                        = f2bf((acc[mt][nt][rr] + cadd[nt]) * qs);
    } else {
        #pragma unroll
        for (int mt = 0; mt < 2; mt++)
            #pragma unroll
            for (int rr = 0; rr < 4; rr++) {
                int d = col0 + wm * 32 + mt * 16 + q * 4 + rr;
                float radd = bias[d] + tc[b * CIN + 2 * CX + d];
                #pragma unroll
                for (int nt = 0; nt < 2; nt++)
                    At[(wm * 32 + mt * 16 + q * 4 + rr) * 72 + wn * 32 + nt * 16 + l15]
                        = f2bf(acc[mt][nt][rr] + radd);
            }
    }
    __syncthreads();
    short8 v0 = *(const short8*)(At + srow * 72 + sch);
    short8 v1 = *(const short8*)(At + srow * 72 + sch + 8);
    if (!OV) {
        short* outp = (which == 0) ? qb : kb;
        size_t off = (size_t)(b * HW_TOT + hw0 + srow) * CX + col0 + sch;
        *(short8*)(outp + off) = v0;
        *(short8*)(outp + off + 8) = v1;
    } else {
        size_t off = (size_t)(b * CX + col0 + srow) * HW_TOT + hw0 + sch;
        *(short8*)(vb + off) = v0;
        *(short8*)(vb + off + 8) = v1;
    }
}

// ---------------------------------------------------------------------------
// Kernel 4: flash attention, wave-split-j: block = 64 qi; waves 0,2 do keys
// 0-511, waves 1,3 keys 512-1023; each wave owns 32 qi (2 B-frag groups) so
// every K/V fragment read serves 2x rows -> LDS traffic halves vs r10 while
// grid stays 512 blocks (3 blocks/CU at 46 KB LDS). Fixed-max softmax makes
// j-half partials combine by addition via an LDS epilogue (no global
// partials, no fences). Q pre-scaled (p=exp2f(s)), ones-MFMA l-sum,
// V swizzled for b128 A-frags, fused residual. Grid (16 qt, 32 bh) x 256.
// ---------------------------------------------------------------------------
__global__ __launch_bounds__(256, 3)
void attn_kernel(const short* __restrict__ qb, const short* __restrict__ kb,
                 const short* __restrict__ vb, const float* __restrict__ x,
                 float* __restrict__ out) {
    const int qt = blockIdx.x, bh = blockIdx.y;
    const int b = bh >> 2, h = bh & 3;
    const int hw0 = qt * 64;

    __shared__ short Qs[64 * 72];
    __shared__ short Ks[2][64 * 72];   // [j-half]
    __shared__ short Vs[2][64 * 72];

    const int t = threadIdx.x;
    const int w = t >> 6, l = t & 63;
    const int pair = w >> 1, jh = w & 1;
    const int l15 = l & 15, q = l >> 4;
    const int srow = t >> 2, sch = (t & 3) * 16;
    const int vpos0 = ((sch >> 5) << 5) + ((sch >> 4) & 1) * 4;   // kcc*32+sub*4

    {   // stage Q tile [qi][c]
        const short* gq = qb + (size_t)(b * HW_TOT + hw0 + srow) * CX + h * CHD + sch;
        *(short8*)(Qs + srow * 72 + sch)     = *(const short8*)gq;
        *(short8*)(Qs + srow * 72 + sch + 8) = *(const short8*)(gq + 8);
    }

    // stage first tile of EACH j-half (block-cooperative; waves read own half)
    short8 pk[2][2], pv[2][2];
    #pragma unroll
    for (int s = 0; s < 2; s++) {
        const int j0 = s * 512;
        const short* gk = kb + (size_t)(b * HW_TOT + j0 + srow) * CX + h * CHD + sch;
        pk[s][0] = *(const short8*)gk;
        pk[s][1] = *(const short8*)(gk + 8);
        const short* gv = vb + (size_t)(b * CX + h * CHD + srow) * HW_TOT + j0 + sch;
        pv[s][0] = *(const short8*)gv;
        pv[s][1] = *(const short8*)(gv + 8);
    }
    #pragma unroll
    for (int s = 0; s < 2; s++) {
        *(short8*)(Ks[s] + srow * 72 + sch)     = pk[s][0];
        *(short8*)(Ks[s] + srow * 72 + sch + 8) = pk[s][1];
        short* vrow = Vs[s] + srow * 72 + vpos0;
        *(s4v*)(vrow)      = __builtin_shufflevector(pv[s][0], pv[s][0], 0, 1, 2, 3);
        *(s4v*)(vrow + 8)  = __builtin_shufflevector(pv[s][0], pv[s][0], 4, 5, 6, 7);
        *(s4v*)(vrow + 16) = __builtin_shufflevector(pv[s][1], pv[s][1], 0, 1, 2, 3);
        *(s4v*)(vrow + 24) = __builtin_shufflevector(pv[s][1], pv[s][1], 4, 5, 6, 7);
    }
    __syncthreads();

    // Q fragments: this wave's 2 qi-groups, qi = pair*32 + g*16 + l15
    short8 aq[2][2];
    #pragma unroll
    for (int g = 0; g < 2; g++) {
        aq[g][0] = *(const short8*)(Qs + (pair * 32 + g * 16 + l15) * 72 + q * 8);
        aq[g][1] = *(const short8*)(Qs + (pair * 32 + g * 16 + l15) * 72 + 32 + q * 8);
    }

    union { int4v i; short8 s; } ones;
    ones.i[0] = 0x3f803f80; ones.i[1] = 0x3f803f80;
    ones.i[2] = 0x3f803f80; ones.i[3] = 0x3f803f80;

    floatx4 oacc[2][4] = {};
    floatx4 lacc[2] = {};
    const short* Kc = Ks[jh];
    const short* Vc = Vs[jh];

    for (int jj = 0; jj < 8; jj++) {
        if (jj < 7) {   // prefetch next tile of each half into regs
            #pragma unroll
            for (int s = 0; s < 2; s++) {
                const int j0 = s * 512 + (jj + 1) * 64;
                const short* gk = kb + (size_t)(b * HW_TOT + j0 + srow) * CX + h * CHD + sch;
                pk[s][0] = *(const short8*)gk;
                pk[s][1] = *(const short8*)(gk + 8);
                const short* gv = vb + (size_t)(b * CX + h * CHD + srow) * HW_TOT + j0 + sch;
                pv[s][0] = *(const short8*)gv;
                pv[s][1] = *(const short8*)(gv + 8);
            }
        }

        // S^T = K . Q'^T : K frags shared across both qi-groups
        floatx4 sacc[2][4] = {};
        #pragma unroll
        for (int nt = 0; nt < 4; nt++) {
            short8 kf0 = *(const short8*)(Kc + (nt * 16 + l15) * 72 + q * 8);
            short8 kf1 = *(const short8*)(Kc + (nt * 16 + l15) * 72 + 32 + q * 8);
            #pragma unroll
            for (int g = 0; g < 2; g++) {
                sacc[g][nt] = __builtin_amdgcn_mfma_f32_16x16x32_bf16(kf0, aq[g][0], sacc[g][nt], 0, 0, 0);
                sacc[g][nt] = __builtin_amdgcn_mfma_f32_16x16x32_bf16(kf1, aq[g][1], sacc[g][nt], 0, 0, 0);
            }
        }

        // p = exp2(s'); truncating pack into B-operand registers
        union { int4v i; short8 s; } u[2][2];
        #pragma unroll
        for (int g = 0; g < 2; g++)
            #pragma unroll
            for (int nt = 0; nt < 4; nt++) {
                float e0 = exp2f(sacc[g][nt][0]);
                float e1 = exp2f(sacc[g][nt][1]);
                float e2 = exp2f(sacc[g][nt][2]);
                float e3 = exp2f(sacc[g][nt][3]);
                u[g][nt >> 1].i[(nt & 1) * 2]     = pack_trunc(e0, e1);
                u[g][nt >> 1].i[(nt & 1) * 2 + 1] = pack_trunc(e2, e3);
            }

        // l += 1^T . P
        #pragma unroll
        for (int g = 0; g < 2; g++) {
            lacc[g] = __builtin_amdgcn_mfma_f32_16x16x32_bf16(ones.s, u[g][0].s, lacc[g], 0, 0, 0);
            lacc[g] = __builtin_amdgcn_mfma_f32_16x16x32_bf16(ones.s, u[g][1].s, lacc[g], 0, 0, 0);
        }

        // O^T += V^T . P : V frags (b128, swizzled) shared across groups
        #pragma unroll
        for (int ct = 0; ct < 4; ct++) {
            const short* vr = Vc + (ct * 16 + l15) * 72;
            #pragma unroll
            for (int kcc = 0; kcc < 2; kcc++) {
                short8 vf = *(const short8*)(vr + kcc * 32 + q * 8);
                #pragma unroll
                for (int g = 0; g < 2; g++)
                    oacc[g][ct] = __builtin_amdgcn_mfma_f32_16x16x32_bf16(
                        vf, u[g][kcc].s, oacc[g][ct], 0, 0, 0);
            }
        }

        if (jj < 7) {
            __syncthreads();   // all waves done reading current tiles
            #pragma unroll
            for (int s = 0; s < 2; s++) {
                *(short8*)(Ks[s] + srow * 72 + sch)     = pk[s][0];
                *(short8*)(Ks[s] + srow * 72 + sch + 8) = pk[s][1];
                short* vrow = Vs[s] + srow * 72 + vpos0;
                *(s4v*)(vrow)      = __builtin_shufflevector(pv[s][0], pv[s][0], 0, 1, 2, 3);
                *(s4v*)(vrow + 8)  = __builtin_shufflevector(pv[s][0], pv[s][0], 4, 5, 6, 7);
                *(s4v*)(vrow + 16) = __builtin_shufflevector(pv[s][1], pv[s][1], 0, 1, 2, 3);
                *(s4v*)(vrow + 24) = __builtin_shufflevector(pv[s][1], pv[s][1], 4, 5, 6, 7);
            }
            __syncthreads();   // writes visible
        }
    }

    // cross-half combine through LDS (fixed-max => pure addition), then
    // normalize + residual + out. Of aliases Ks (17.4 KB), Lf aliases Vs.
    __syncthreads();
    float* Of = (float*)Ks;            // [qi][c] stride 68
    float* Lf = (float*)Vs;            // [qi]
    if (jh == 1) {
        #pragma unroll
        for (int g = 0; g < 2; g++) {
            int qi = pair * 32 + g * 16 + l15;
            #pragma unroll
            for (int ct = 0; ct < 4; ct++)
                *(floatx4*)&Of[qi * 68 + ct * 16 + q * 4] = oacc[g][ct];
            if (q == 0) Lf[qi] = lacc[g][0];
        }
    }
    __syncthreads();
    if (jh == 0) {
        #pragma unroll
        for (int g = 0; g < 2; g++) {
            int qi = pair * 32 + g * 16 + l15;
            const float rinv = 1.f / (lacc[g][0] + Lf[qi]);
            #pragma unroll
            for (int ct = 0; ct < 4; ct++) {
                floatx4 po = *(const floatx4*)&Of[qi * 68 + ct * 16 + q * 4];
                #pragma unroll
                for (int r = 0; r < 4; r++) {
                    int c = h * CHD + ct * 16 + q * 4 + r;
                    size_t idx = (size_t)(b * CX + c) * HW_TOT + hw0 + qi;
                    out[idx] = x[idx] + (oacc[g][ct][r] + po[r]) * rinv;
                }
            }
        }
    }
}

// ---------------------------------------------------------------------------
extern "C" void kernel_launch(void* const* d_in, const int* in_sizes, int n_in,
                              void* d_out, int out_size, void* d_ws, size_t ws_size,
                              hipStream_t stream) {
    (void)in_sizes; (void)n_in; (void)out_size; (void)ws_size;
    const float* x     = (const float*)d_in[0];
    const float* tf    = (const float*)d_in[1];
    const float* gamma = (const float*)d_in[2];
    const float* beta  = (const float*)d_in[3];
    const float* W0 = (const float*)d_in[4];
    const float* b0 = (const float*)d_in[5];
    const float* W1 = (const float*)d_in[6];
    const float* b1 = (const float*)d_in[7];
    const float* W2 = (const float*)d_in[8];
    const float* b2 = (const float*)d_in[9];

    char* ws = (char*)d_ws;
    float* scale  = (float*)(ws);                 // 24576 B
    float* shift  = (float*)(ws + 24576);         // 24576 B
    float* tcb    = (float*)(ws + 49152);         // 24576 B
    short* Wt     = (short*)(ws + 73728);         // 393216 B
    short* hnT    = (short*)(ws + 466944);        // 4 MiB
    short* qb     = (short*)(ws + 4661248);       // 4 MiB
    short* kb     = (short*)(ws + 8855552);       // 4 MiB
    short* vb     = (short*)(ws + 13049856);      // 4 MiB

    hipLaunchKernelGGL(gn_kernel, dim3(256), dim3(256), 0, stream,
                       x, tf, gamma, beta, scale, shift, tcb);
    hipLaunchKernelGGL(prep_kernel, dim3(652), dim3(256), 0, stream,
                       x, tf, scale, shift, W0, W1, W2, hnT, Wt, tcb);
    hipLaunchKernelGGL(qkv_gemm, dim3(16, 12, BATCH), dim3(256), 0, stream,
                       hnT, Wt, tcb, b0, b1, b2, qb, kb, vb);
    hipLaunchKernelGGL(attn_kernel, dim3(16, 32), dim3(256), 0, stream,
                       qb, kb, vb, x, (float*)d_out);
}